// Round 5
// baseline (490.500 us; speedup 1.0000x reference)
//
#include <hip/hip_runtime.h>

// ---------------------------------------------------------------------------
// VGAE encoder, fully fused per-layer pipeline.
//   Agg(h@W) == Agg(h)@W ; norm_e = dis_dst*dis_src factorized into the g
//   table (g = dis (.) h). Per layer, ONE kernel does:
//     a_row = dis_i*(g[i] + sum g[src_e])   (register/LDS)
//     h     = relu(a_row @ W + b)           (in-block GEMM via LDS)
//     g_out = dis_i (.) h                   (written once)
//   Final layer computes mu|logvar (64 ch) directly to d_out.
//   Preprocessing: 3-kernel bucketed counting sort by dst (bucket bases
//   re-derived by LDS scans; g0 = dis (.) x folded into finalize).
// ---------------------------------------------------------------------------

#define BK_BITS 9
#define BK      (1 << BK_BITS)     // 512 dst nodes per bucket
#define BMASK   (BK - 1)
#define EPT     16
#define CHUNK   (256 * EPT)        // 4096 edges per block

// ---- pass 0: count edges per coarse bucket ---------------------------------
__global__ void k_bcnt(const int* __restrict__ dst, int E, int* __restrict__ bcnt) {
    __shared__ int lcnt[256];
    int t = threadIdx.x;
    lcnt[t] = 0;
    __syncthreads();
    int e0 = blockIdx.x * CHUNK;
#pragma unroll
    for (int i = 0; i < EPT; ++i) {
        int e = e0 + i * 256 + t;
        if (e < E) atomicAdd(&lcnt[dst[e] >> BK_BITS], 1);
    }
    __syncthreads();
    if (lcnt[t]) atomicAdd(&bcnt[t], lcnt[t]);
}

// ---- pass A: scatter edges into dst-buckets (block-grouped writes) ---------
// ebuf[pos] = (src << BK_BITS) | (dst & BMASK); bucket base derived by LDS scan.
__global__ void k_bucket(const int* __restrict__ src, const int* __restrict__ dst,
                         const int* __restrict__ bcnt, int* __restrict__ bcur,
                         int* __restrict__ ebuf, int E) {
    __shared__ int lcnt[256];
    __shared__ int sb[256];
    __shared__ int lbase[256];
    int t = threadIdx.x;
    lcnt[t] = 0;
    sb[t] = bcnt[t];
    __syncthreads();
    for (int o = 1; o < 256; o <<= 1) {
        int xv = (t >= o) ? sb[t - o] : 0;
        __syncthreads();
        sb[t] += xv;
        __syncthreads();
    }
    int bbase = sb[t] - bcnt[t];           // exclusive
    int e0 = blockIdx.x * CHUNK;
    int pk[EPT];
#pragma unroll
    for (int i = 0; i < EPT; ++i) {
        int e = e0 + i * 256 + t;
        pk[i] = -1;
        if (e < E) {
            int d = dst[e];
            int b = d >> BK_BITS;
            int off = atomicAdd(&lcnt[b], 1);          // off < CHUNK = 4096
            pk[i] = (b << 21) | (off << BK_BITS) | (d & BMASK);
        }
    }
    __syncthreads();
    lbase[t] = bbase + atomicAdd(&bcur[t], lcnt[t]);
    __syncthreads();
#pragma unroll
    for (int i = 0; i < EPT; ++i) {
        int e = e0 + i * 256 + t;
        if (e < E) {
            int b   = pk[i] >> 21;
            int off = (pk[i] >> BK_BITS) & 4095;
            int dl  = pk[i] & BMASK;
            ebuf[lbase[b] + off] = (src[e] << BK_BITS) | dl;
        }
    }
}

// ---- pass B: per-bucket finalize: starts, dis, sorted src array, g0 --------
// one 512-thread block per bucket; per-dst hist/scan/cursor all in LDS.
__global__ void k_finalize(const int* __restrict__ bcnt, int* __restrict__ starts,
                           float* __restrict__ dis, const int* __restrict__ ebuf,
                           int* __restrict__ es, const float* __restrict__ x,
                           float* __restrict__ g0, int n, int E) {
    __shared__ int   hist[BK];
    __shared__ int   sc[BK];
    __shared__ int   sb[256];
    __shared__ float disL[BK];
    int b = blockIdx.x, t = threadIdx.x;
    if (t < 256) sb[t] = bcnt[t];
    hist[t] = 0;
    __syncthreads();
    for (int o = 1; o < 256; o <<= 1) {
        int xv = 0;
        if (t < 256 && t >= o) xv = sb[t - o];
        __syncthreads();
        if (t < 256) sb[t] += xv;
        __syncthreads();
    }
    int end = sb[b];                        // inclusive scan at b
    int beg = end - bcnt[b];
    // per-dst histogram
    for (int j = beg + t; j < end; j += BK)
        atomicAdd(&hist[ebuf[j] & BMASK], 1);
    __syncthreads();
    int cv = hist[t];
    sc[t] = cv;
    __syncthreads();
    for (int o = 1; o < BK; o <<= 1) {
        int xv = (t >= o) ? sc[t - o] : 0;
        __syncthreads();
        sc[t] += xv;
        __syncthreads();
    }
    int excl = sc[t] - cv;
    int gnode = (b << BK_BITS) + t;
    float dv = rsqrtf((float)cv + 1.0f);    // +1 = self loop
    disL[t] = dv;
    if (gnode < n) {
        starts[gnode] = beg + excl;
        dis[gnode] = dv;
    }
    if (b == 0 && t == 0) starts[n] = E;
    hist[t] = excl;                         // reuse as cursor
    __syncthreads();
    // sorted src-only edge array (writes stay in bucket window)
    for (int j = beg + t; j < end; j += BK) {
        int v = ebuf[j];
        int off = atomicAdd(&hist[v & BMASK], 1);
        es[beg + off] = v >> BK_BITS;
    }
    // g0 = dis (.) x for this bucket's nodes (coalesced)
    int node0 = b << BK_BITS;
    const float4* x4 = (const float4*)x;
    float4* g4 = (float4*)g0;
    for (int idx = t; idx < BK * 8; idx += BK) {
        int r = idx >> 3, lane = idx & 7;
        int nd = node0 + r;
        if (nd < n) {
            float d = disL[r];
            float4 v = x4[(size_t)nd * 8 + lane];
            v.x *= d; v.y *= d; v.z *= d; v.w *= d;
            g4[(size_t)nd * 8 + lane] = v;
        }
    }
}

// ---- fused layer: a = dis*(g[i]+sum g[src]); gout = dis*relu(a@W+b) --------
// 256 threads = 32 nodes x 8 lanes (float4 each)
__global__ void k_layer32(const int* __restrict__ starts, const int* __restrict__ es,
                          const float* __restrict__ dis, const float* __restrict__ g,
                          const float* __restrict__ W, const float* __restrict__ bias,
                          float* __restrict__ gout, int n) {
    __shared__ float Ws[32][33];
    __shared__ float As[32][36];
    int t = threadIdx.x;
    for (int i = t; i < 1024; i += 256) Ws[i >> 5][i & 31] = W[i];
    int r = t >> 3, lane = t & 7;
    int node = blockIdx.x * 32 + r;
    float4 a = make_float4(0.f, 0.f, 0.f, 0.f);
    float dd = 0.f;
    const float4* g4 = (const float4*)g;
    if (node < n) {
        a = g4[(size_t)node * 8 + lane];
        int j = starts[node], end = starts[node + 1];
        for (; j + 3 < end; j += 4) {
            int s0 = es[j], s1 = es[j + 1], s2 = es[j + 2], s3 = es[j + 3];
            float4 v0 = g4[(size_t)s0 * 8 + lane];
            float4 v1 = g4[(size_t)s1 * 8 + lane];
            float4 v2 = g4[(size_t)s2 * 8 + lane];
            float4 v3 = g4[(size_t)s3 * 8 + lane];
            a.x += v0.x; a.y += v0.y; a.z += v0.z; a.w += v0.w;
            a.x += v1.x; a.y += v1.y; a.z += v1.z; a.w += v1.w;
            a.x += v2.x; a.y += v2.y; a.z += v2.z; a.w += v2.w;
            a.x += v3.x; a.y += v3.y; a.z += v3.z; a.w += v3.w;
        }
        for (; j < end; ++j) {
            float4 v = g4[(size_t)es[j] * 8 + lane];
            a.x += v.x; a.y += v.y; a.z += v.z; a.w += v.w;
        }
        dd = dis[node];
        a.x *= dd; a.y *= dd; a.z *= dd; a.w *= dd;
    }
    *(float4*)&As[r][lane * 4] = a;
    __syncthreads();
    if (node >= n) return;
    const float* row = As[r];
    int c0 = lane * 4;
    float4 bb = ((const float4*)bias)[lane];
    float s0 = bb.x, s1 = bb.y, s2 = bb.z, s3 = bb.w;
#pragma unroll
    for (int k = 0; k < 32; ++k) {
        float rk = row[k];
        s0 += rk * Ws[k][c0];
        s1 += rk * Ws[k][c0 + 1];
        s2 += rk * Ws[k][c0 + 2];
        s3 += rk * Ws[k][c0 + 3];
    }
    float4 res = make_float4(dd * fmaxf(s0, 0.f), dd * fmaxf(s1, 0.f),
                             dd * fmaxf(s2, 0.f), dd * fmaxf(s3, 0.f));
    ((float4*)gout)[(size_t)node * 8 + lane] = res;
}

// ---- fused final layer: a = dis*(g[i]+sum); out = a@[Wmu|Wlv]+bias ---------
__global__ void k_layer64(const int* __restrict__ starts, const int* __restrict__ es,
                          const float* __restrict__ dis, const float* __restrict__ g,
                          const float* __restrict__ Wmu, const float* __restrict__ Wlv,
                          const float* __restrict__ bmu, const float* __restrict__ blv,
                          float* __restrict__ out, int n) {
    __shared__ float Ws[32][64];
    __shared__ float As[32][36];
    int t = threadIdx.x;
    for (int i = t; i < 1024; i += 256) {
        int k = i >> 5, c = i & 31;
        Ws[k][c]      = Wmu[i];
        Ws[k][c + 32] = Wlv[i];
    }
    int r = t >> 3, lane = t & 7;
    int node = blockIdx.x * 32 + r;
    float4 a = make_float4(0.f, 0.f, 0.f, 0.f);
    const float4* g4 = (const float4*)g;
    if (node < n) {
        a = g4[(size_t)node * 8 + lane];
        int j = starts[node], end = starts[node + 1];
        for (; j + 3 < end; j += 4) {
            int s0 = es[j], s1 = es[j + 1], s2 = es[j + 2], s3 = es[j + 3];
            float4 v0 = g4[(size_t)s0 * 8 + lane];
            float4 v1 = g4[(size_t)s1 * 8 + lane];
            float4 v2 = g4[(size_t)s2 * 8 + lane];
            float4 v3 = g4[(size_t)s3 * 8 + lane];
            a.x += v0.x; a.y += v0.y; a.z += v0.z; a.w += v0.w;
            a.x += v1.x; a.y += v1.y; a.z += v1.z; a.w += v1.w;
            a.x += v2.x; a.y += v2.y; a.z += v2.z; a.w += v2.w;
            a.x += v3.x; a.y += v3.y; a.z += v3.z; a.w += v3.w;
        }
        for (; j < end; ++j) {
            float4 v = g4[(size_t)es[j] * 8 + lane];
            a.x += v.x; a.y += v.y; a.z += v.z; a.w += v.w;
        }
        float dd = dis[node];
        a.x *= dd; a.y *= dd; a.z *= dd; a.w *= dd;
    }
    *(float4*)&As[r][lane * 4] = a;
    __syncthreads();
    if (node >= n) return;
    const float* row = As[r];
    int c0 = lane * 8;
    float s[8];
#pragma unroll
    for (int i = 0; i < 8; ++i)
        s[i] = (c0 < 32) ? bmu[c0 + i] : blv[c0 - 32 + i];
#pragma unroll
    for (int k = 0; k < 32; ++k) {
        float rk = row[k];
#pragma unroll
        for (int i = 0; i < 8; ++i) s[i] += rk * Ws[k][c0 + i];
    }
    float* dstp = (c0 < 32) ? (out + (size_t)node * 32 + c0)
                            : (out + (size_t)n * 32 + (size_t)node * 32 + (c0 - 32));
    *(float4*)dstp       = make_float4(s[0], s[1], s[2], s[3]);
    *(float4*)(dstp + 4) = make_float4(s[4], s[5], s[6], s[7]);
}

// ---- launch ----------------------------------------------------------------

extern "C" void kernel_launch(void* const* d_in, const int* in_sizes, int n_in,
                              void* d_out, int out_size, void* d_ws, size_t ws_size,
                              hipStream_t stream) {
    const float* x   = (const float*)d_in[0];
    const int*   ei  = (const int*)d_in[1];
    const float* W1  = (const float*)d_in[2];
    const float* b1  = (const float*)d_in[3];
    const float* W2  = (const float*)d_in[4];
    const float* b2  = (const float*)d_in[5];
    const float* Wmu = (const float*)d_in[6];
    const float* bmu = (const float*)d_in[7];
    const float* Wlv = (const float*)d_in[8];
    const float* blv = (const float*)d_in[9];
    float* out = (float*)d_out;

    int n = in_sizes[0] / 32;   // 100000
    int E = in_sizes[1] / 2;    // 1600000
    const int* src = ei;
    const int* dst = ei + E;
    int nbuck = (n + BK - 1) >> BK_BITS;   // 196 (<= 256)

    // workspace layout
    int*   bcnt   = (int*)d_ws;                    // 256
    int*   bcur   = bcnt + 256;                    // 256
    int    npad   = (n + 4) & ~3;
    int*   starts = bcur + 256;                    // n+1 (padded)
    float* dis    = (float*)(starts + npad);       // n
    int*   es     = (int*)(dis + n);               // E
    int*   ebuf   = es + E;                        // E
    float* gA     = (float*)(ebuf + E);            // n*32
    float* gB     = gA + (size_t)n * 32;           // n*32

    int nblk = (E + CHUNK - 1) / CHUNK;
    int lgrid = (n + 31) / 32;

    // ---- edge preprocessing ----
    hipMemsetAsync(bcnt, 0, 512 * sizeof(int), stream);
    k_bcnt<<<nblk, 256, 0, stream>>>(dst, E, bcnt);
    k_bucket<<<nblk, 256, 0, stream>>>(src, dst, bcnt, bcur, ebuf, E);
    k_finalize<<<nbuck, BK, 0, stream>>>(bcnt, starts, dis, ebuf, es, x, gA, n, E);

    // ---- fused layers ----
    k_layer32<<<lgrid, 256, 0, stream>>>(starts, es, dis, gA, W1, b1, gB, n);
    k_layer32<<<lgrid, 256, 0, stream>>>(starts, es, dis, gB, W2, b2, gA, n);
    k_layer64<<<lgrid, 256, 0, stream>>>(starts, es, dis, gA, Wmu, Wlv, bmu, blv, out, n);
}

// Round 6
// 306.231 us; speedup vs baseline: 1.6017x; 1.6017x over previous
//
#include <hip/hip_runtime.h>
#include <hip/hip_fp16.h>

// ---------------------------------------------------------------------------
// VGAE encoder, gather-form, fp16 gather table.
//   Agg(h@W) == Agg(h)@W ; norm_e = dis_dst*dis_src factorized:
//     a[i] = dis_i * ( g[i] + sum_{e:dst=i} g[src_e] ),  g = fp16(dis (.) h)
//   g rows are 64 B (one cache line) -> halves random-gather traffic.
//   Split kernels (agg: 0 LDS, high occupancy; gemm: LDS tile) — fusion
//   regressed in R5 (occupancy/locality collapse).
//   Preprocessing: 3-kernel bucketed counting sort by dst.
// ---------------------------------------------------------------------------

#define BK_BITS 9
#define BK      (1 << BK_BITS)     // 512 dst nodes per bucket
#define BMASK   (BK - 1)
#define EPT     16
#define CHUNK   (256 * EPT)        // 4096 edges per block

// ---- pass 0: count edges per coarse bucket ---------------------------------
__global__ void k_bcnt(const int* __restrict__ dst, int E, int* __restrict__ bcnt) {
    __shared__ int lcnt[256];
    int t = threadIdx.x;
    lcnt[t] = 0;
    __syncthreads();
    int e0 = blockIdx.x * CHUNK;
#pragma unroll
    for (int i = 0; i < EPT; ++i) {
        int e = e0 + i * 256 + t;
        if (e < E) atomicAdd(&lcnt[dst[e] >> BK_BITS], 1);
    }
    __syncthreads();
    if (lcnt[t]) atomicAdd(&bcnt[t], lcnt[t]);
}

// ---- pass A: scatter edges into dst-buckets (block-grouped writes) ---------
// ebuf[pos] = (src << BK_BITS) | (dst & BMASK); bucket base via LDS scan.
__global__ void k_bucket(const int* __restrict__ src, const int* __restrict__ dst,
                         const int* __restrict__ bcnt, int* __restrict__ bcur,
                         int* __restrict__ ebuf, int E) {
    __shared__ int lcnt[256];
    __shared__ int sb[256];
    __shared__ int lbase[256];
    int t = threadIdx.x;
    lcnt[t] = 0;
    sb[t] = bcnt[t];
    __syncthreads();
    for (int o = 1; o < 256; o <<= 1) {
        int xv = (t >= o) ? sb[t - o] : 0;
        __syncthreads();
        sb[t] += xv;
        __syncthreads();
    }
    int bbase = sb[t] - bcnt[t];           // exclusive
    int e0 = blockIdx.x * CHUNK;
    int pk[EPT];
#pragma unroll
    for (int i = 0; i < EPT; ++i) {
        int e = e0 + i * 256 + t;
        pk[i] = -1;
        if (e < E) {
            int d = dst[e];
            int b = d >> BK_BITS;
            int off = atomicAdd(&lcnt[b], 1);          // off < CHUNK = 4096
            pk[i] = (b << 21) | (off << BK_BITS) | (d & BMASK);
        }
    }
    __syncthreads();
    lbase[t] = bbase + atomicAdd(&bcur[t], lcnt[t]);
    __syncthreads();
#pragma unroll
    for (int i = 0; i < EPT; ++i) {
        int e = e0 + i * 256 + t;
        if (e < E) {
            int b   = pk[i] >> 21;
            int off = (pk[i] >> BK_BITS) & 4095;
            int dl  = pk[i] & BMASK;
            ebuf[lbase[b] + off] = (src[e] << BK_BITS) | dl;
        }
    }
}

// ---- pass B: per-bucket finalize: starts, dis, sorted src, g0 = fp16(dis.x) -
__global__ void k_finalize(const int* __restrict__ bcnt, int* __restrict__ starts,
                           float* __restrict__ dis, const int* __restrict__ ebuf,
                           int* __restrict__ es, const float* __restrict__ x,
                           __half* __restrict__ g0, int n, int E) {
    __shared__ int   hist[BK];
    __shared__ int   sc[BK];
    __shared__ int   sb[256];
    __shared__ float disL[BK];
    int b = blockIdx.x, t = threadIdx.x;
    if (t < 256) sb[t] = bcnt[t];
    hist[t] = 0;
    __syncthreads();
    for (int o = 1; o < 256; o <<= 1) {
        int xv = 0;
        if (t < 256 && t >= o) xv = sb[t - o];
        __syncthreads();
        if (t < 256) sb[t] += xv;
        __syncthreads();
    }
    int end = sb[b];                        // inclusive scan at b
    int beg = end - bcnt[b];
    for (int j = beg + t; j < end; j += BK)
        atomicAdd(&hist[ebuf[j] & BMASK], 1);
    __syncthreads();
    int cv = hist[t];
    sc[t] = cv;
    __syncthreads();
    for (int o = 1; o < BK; o <<= 1) {
        int xv = (t >= o) ? sc[t - o] : 0;
        __syncthreads();
        sc[t] += xv;
        __syncthreads();
    }
    int excl = sc[t] - cv;
    int gnode = (b << BK_BITS) + t;
    float dv = rsqrtf((float)cv + 1.0f);    // +1 = self loop
    disL[t] = dv;
    if (gnode < n) {
        starts[gnode] = beg + excl;
        dis[gnode] = dv;
    }
    if (b == 0 && t == 0) starts[n] = E;
    hist[t] = excl;                         // reuse as cursor
    __syncthreads();
    for (int j = beg + t; j < end; j += BK) {
        int v = ebuf[j];
        int off = atomicAdd(&hist[v & BMASK], 1);
        es[beg + off] = v >> BK_BITS;
    }
    // g0 = fp16(dis (.) x) for this bucket's nodes (coalesced 8 B stores)
    int node0 = b << BK_BITS;
    const float4* x4 = (const float4*)x;
    uint2* g2 = (uint2*)g0;                 // 8 B = 4 halves
    for (int idx = t; idx < BK * 8; idx += BK) {
        int r = idx >> 3, lane = idx & 7;
        int nd = node0 + r;
        if (nd < n) {
            float d = disL[r];
            float4 v = x4[(size_t)nd * 8 + lane];
            __half2 lo = __floats2half2_rn(d * v.x, d * v.y);
            __half2 hi = __floats2half2_rn(d * v.z, d * v.w);
            uint2 u;
            u.x = *(unsigned int*)&lo;
            u.y = *(unsigned int*)&hi;
            g2[(size_t)nd * 8 + lane] = u;
        }
    }
}

// ---- aggregation: a[i] = dis_i*(g[i] + sum g[src_e]), fp32 accum -----------
// 4 lanes/node, each lane loads 16 B (8 halves); 256 threads = 64 nodes
__device__ inline void acc8(uint4 u, float* s) {
    __half2 h0 = *(__half2*)&u.x, h1 = *(__half2*)&u.y;
    __half2 h2 = *(__half2*)&u.z, h3 = *(__half2*)&u.w;
    float2 f0 = __half22float2(h0), f1 = __half22float2(h1);
    float2 f2 = __half22float2(h2), f3 = __half22float2(h3);
    s[0] += f0.x; s[1] += f0.y; s[2] += f1.x; s[3] += f1.y;
    s[4] += f2.x; s[5] += f2.y; s[6] += f3.x; s[7] += f3.y;
}

__global__ void k_agg(const int* __restrict__ starts, const int* __restrict__ es,
                      const float* __restrict__ dis, const __half* __restrict__ g,
                      float* __restrict__ out, int n) {
    int t = threadIdx.x;
    int node = blockIdx.x * 64 + (t >> 2);
    if (node >= n) return;
    int lane = t & 3;
    const uint4* g4 = (const uint4*)g;     // 16 B = 8 halves
    float s[8] = {0, 0, 0, 0, 0, 0, 0, 0};
    acc8(g4[(size_t)node * 4 + lane], s);  // self term
    int j = starts[node], end = starts[node + 1];
    for (; j + 3 < end; j += 4) {
        uint4 u0 = g4[(size_t)es[j] * 4 + lane];
        uint4 u1 = g4[(size_t)es[j + 1] * 4 + lane];
        uint4 u2 = g4[(size_t)es[j + 2] * 4 + lane];
        uint4 u3 = g4[(size_t)es[j + 3] * 4 + lane];
        acc8(u0, s); acc8(u1, s); acc8(u2, s); acc8(u3, s);
    }
    for (; j < end; ++j) acc8(g4[(size_t)es[j] * 4 + lane], s);
    float dd = dis[node];
    float4 o0 = make_float4(dd * s[0], dd * s[1], dd * s[2], dd * s[3]);
    float4 o1 = make_float4(dd * s[4], dd * s[5], dd * s[6], dd * s[7]);
    float4* op = (float4*)out + (size_t)node * 8 + lane * 2;
    op[0] = o0;
    op[1] = o1;
}

// ---- dense layers ----------------------------------------------------------

// gout = fp16(dis (.) relu(in @ W + b)) ; 256 threads = 8 nodes x 32 channels
__global__ void k_gemm32(const float* __restrict__ in, const float* __restrict__ W,
                         const float* __restrict__ b, const float* __restrict__ dis,
                         __half* __restrict__ gout, int n) {
    __shared__ float Ws[32][33];
    __shared__ float Xs[8][33];
    int t = threadIdx.x;
    for (int i = t; i < 1024; i += 256) Ws[i >> 5][i & 31] = W[i];
    int r = t >> 5, c = t & 31;
    int node = blockIdx.x * 8 + r;
    Xs[r][c] = (node < n) ? in[node * 32 + c] : 0.f;
    __syncthreads();
    if (node >= n) return;
    float sum = b[c];
#pragma unroll
    for (int k = 0; k < 32; ++k) sum += Xs[r][k] * Ws[k][c];
    gout[(size_t)node * 32 + c] = __float2half_rn(dis[node] * fmaxf(sum, 0.f));
}

// mu = in@Wmu + bmu -> out[0:n*32] ; lv = in@Wlv + blv -> out[n*32:]
__global__ void k_gemm64(const float* __restrict__ in, const float* __restrict__ Wmu,
                         const float* __restrict__ Wlv, const float* __restrict__ bmu,
                         const float* __restrict__ blv, float* __restrict__ out, int n) {
    __shared__ float Ws[32][64];
    __shared__ float Xs[4][33];
    int t = threadIdx.x;
    for (int i = t; i < 1024; i += 256) {
        int k = i >> 5, c = i & 31;
        Ws[k][c]      = Wmu[i];
        Ws[k][c + 32] = Wlv[i];
    }
    if (t < 128) {
        int r = t >> 5, c = t & 31;
        int node = blockIdx.x * 4 + r;
        Xs[r][c] = (node < n) ? in[node * 32 + c] : 0.f;
    }
    __syncthreads();
    int r = t >> 6, c = t & 63;
    int node = blockIdx.x * 4 + r;
    if (node >= n) return;
    float sum = (c < 32) ? bmu[c] : blv[c - 32];
#pragma unroll
    for (int k = 0; k < 32; ++k) sum += Xs[r][k] * Ws[k][c];
    if (c < 32) out[(size_t)node * 32 + c] = sum;
    else        out[(size_t)n * 32 + (size_t)node * 32 + (c - 32)] = sum;
}

// ---- launch ----------------------------------------------------------------

extern "C" void kernel_launch(void* const* d_in, const int* in_sizes, int n_in,
                              void* d_out, int out_size, void* d_ws, size_t ws_size,
                              hipStream_t stream) {
    const float* x   = (const float*)d_in[0];
    const int*   ei  = (const int*)d_in[1];
    const float* W1  = (const float*)d_in[2];
    const float* b1  = (const float*)d_in[3];
    const float* W2  = (const float*)d_in[4];
    const float* b2  = (const float*)d_in[5];
    const float* Wmu = (const float*)d_in[6];
    const float* bmu = (const float*)d_in[7];
    const float* Wlv = (const float*)d_in[8];
    const float* blv = (const float*)d_in[9];
    float* out = (float*)d_out;

    int n = in_sizes[0] / 32;   // 100000
    int E = in_sizes[1] / 2;    // 1600000
    const int* src = ei;
    const int* dst = ei + E;
    int nbuck = (n + BK - 1) >> BK_BITS;   // 196 (<= 256)

    // workspace layout (all segments 16B-aligned)
    int*    bcnt   = (int*)d_ws;                   // 256
    int*    bcur   = bcnt + 256;                   // 256
    int     npad   = (n + 4) & ~3;
    int*    starts = bcur + 256;                   // n+1 (padded)
    float*  dis    = (float*)(starts + npad);      // n
    int*    es     = (int*)(dis + n);              // E
    float*  a32    = (float*)(es + E);             // n*32 fp32
    __half* gA     = (__half*)(a32 + (size_t)n * 32); // n*32 fp16
    __half* gB     = gA + (size_t)n * 32;          // n*32 fp16
    int*    ebuf   = (int*)a32;                    // E ints (dead before a32 use)

    int nblk = (E + CHUNK - 1) / CHUNK;
    int agrid = (n + 63) / 64;

    // ---- edge preprocessing ----
    hipMemsetAsync(bcnt, 0, 512 * sizeof(int), stream);
    k_bcnt<<<nblk, 256, 0, stream>>>(dst, E, bcnt);
    k_bucket<<<nblk, 256, 0, stream>>>(src, dst, bcnt, bcur, ebuf, E);
    k_finalize<<<nbuck, BK, 0, stream>>>(bcnt, starts, dis, ebuf, es, x, gA, n, E);

    // ---- layer 1 ----
    k_agg<<<agrid, 256, 0, stream>>>(starts, es, dis, gA, a32, n);
    k_gemm32<<<(n + 7) / 8, 256, 0, stream>>>(a32, W1, b1, dis, gB, n);

    // ---- layer 2 ----
    k_agg<<<agrid, 256, 0, stream>>>(starts, es, dis, gB, a32, n);
    k_gemm32<<<(n + 7) / 8, 256, 0, stream>>>(a32, W2, b2, dis, gA, n);

    // ---- mu/logvar ----
    k_agg<<<agrid, 256, 0, stream>>>(starts, es, dis, gA, a32, n);
    k_gemm64<<<(n + 3) / 4, 256, 0, stream>>>(a32, Wmu, Wlv, bmu, blv, out, n);
}